// Round 1
// baseline (103.491 us; speedup 1.0000x reference)
//
#include <hip/hip_runtime.h>

#define M_ROWS 8192   // B*L
#define DIM    768    // D
#define HCH    128    // H

typedef __bf16 bf16x8 __attribute__((ext_vector_type(8)));
typedef float  f32x4  __attribute__((ext_vector_type(4)));

__device__ __forceinline__ unsigned int f2bf(float f) {
    union { float f; unsigned int u; } v; v.f = f;
    unsigned int u = v.u;
    u += 0x7fffu + ((u >> 16) & 1u);   // round-to-nearest-even
    return u >> 16;
}

// pack 8 f32 (two float4) -> 8 bf16 (uint4)
__device__ __forceinline__ uint4 pack8(const float4 a, const float4 b) {
    uint4 o;
    o.x = f2bf(a.x) | (f2bf(a.y) << 16);
    o.y = f2bf(a.z) | (f2bf(a.w) << 16);
    o.z = f2bf(b.x) | (f2bf(b.y) << 16);
    o.w = f2bf(b.z) | (f2bf(b.w) << 16);
    return o;
}

// Fused GEMM (M=8192,N=128,K=768, bf16 MFMA) + relu + weighted H-reduction.
// W0 f32->bf16 conversion folded into the B-staging path (no separate kernel).
// Block: 512 thr = 8 waves in a 2x4 grid over (32 rows x 128 cols). Grid: 256
// (1 block/CU, 2 waves/SIMD -- double the TLP of the old 256-thr version).
__global__ __launch_bounds__(512) void gemm_s_kernel(
    const float* __restrict__ text,
    const float* __restrict__ W0,
    const float* __restrict__ b0,
    const float* __restrict__ W1,
    float* __restrict__ s1, float* __restrict__ s2)
{
    // row stride 40 bf16 = 80 B: b128 frag reads/writes land uniformly on banks
    __shared__ unsigned short As[32][40];
    __shared__ unsigned short Bs[128][40];
    __shared__ float red1[32][4];
    __shared__ float red2[32][4];

    const int tid  = threadIdx.x;
    const int lane = tid & 63;
    const int wave = tid >> 6;          // 0..7
    const int row0 = blockIdx.x * 32;

    const int wrow = (wave >> 2) * 16;  // wave row offset: 0 / 16
    const int wcol = (wave & 3) * 32;   // wave col offset: 0 / 32 / 64 / 96
    const int n16  = lane & 15;
    const int quad = lane >> 4;

    // staging maps: every thread stages 8 k's of one B row; waves 0-1 also
    // stage A (wave-uniform predicate -> no divergence inside a wave)
    const int srow = tid >> 2;          // 0..127
    const int sk8  = (tid & 3) * 8;     // 0, 8, 16, 24
    const float* bptr = W0   + (size_t)srow * DIM + sk8;
    const float* aptr = text + (size_t)(row0 + (srow & 31)) * DIM + sk8;
    const bool doA = (tid < 128);

    f32x4 acc[2];
    acc[0] = (f32x4){0.f, 0.f, 0.f, 0.f};
    acc[1] = (f32x4){0.f, 0.f, 0.f, 0.f};

    float4 bA = *(const float4*)bptr;
    float4 bB = *(const float4*)(bptr + 4);
    float4 aA, aB;
    if (doA) { aA = *(const float4*)aptr; aB = *(const float4*)(aptr + 4); }

    for (int kt = 0; kt < DIM; kt += 32) {
        const int ktn = (kt + 32 < DIM) ? (kt + 32) : 0;   // harmless reload on last iter
        float4 nbA = *(const float4*)(bptr + ktn);
        float4 nbB = *(const float4*)(bptr + ktn + 4);
        float4 naA, naB;
        if (doA) { naA = *(const float4*)(aptr + ktn); naB = *(const float4*)(aptr + ktn + 4); }

        // stage current tile into LDS (f32 -> bf16 on the fly for BOTH A and B)
        *(uint4*)&Bs[srow][sk8] = pack8(bA, bB);
        if (doA) *(uint4*)&As[srow & 31][sk8] = pack8(aA, aB);
        __syncthreads();

        bf16x8 a   = *(const bf16x8*)&As[wrow + n16][quad * 8];
        bf16x8 bf0 = *(const bf16x8*)&Bs[wcol +  0 + n16][quad * 8];
        bf16x8 bf1 = *(const bf16x8*)&Bs[wcol + 16 + n16][quad * 8];
        acc[0] = __builtin_amdgcn_mfma_f32_16x16x32_bf16(a, bf0, acc[0], 0, 0, 0);
        acc[1] = __builtin_amdgcn_mfma_f32_16x16x32_bf16(a, bf1, acc[1], 0, 0, 0);
        __syncthreads();

        bA = nbA; bB = nbB;
        if (doA) { aA = naA; aB = naB; }
    }

    // epilogue: relu + b0, weight by w_a / w_b, reduce over the 128 cols.
    // C/D layout (verified): col = lane&15 (+tile), row = quad*4 + reg
    float p1[4] = {0.f, 0.f, 0.f, 0.f};
    float p2[4] = {0.f, 0.f, 0.f, 0.f};
    #pragma unroll
    for (int j = 0; j < 2; ++j) {
        const int col = wcol + j * 16 + n16;
        const float bb = b0[col];
        const float wa = W1[col];
        const float wb = W1[HCH + col];
        #pragma unroll
        for (int r = 0; r < 4; ++r) {
            float h = acc[j][r] + bb;
            h = fmaxf(h, 0.f);
            p1[r] += h * wa;
            p2[r] += h * wb;
        }
    }
    // reduce across the 16 lanes of each quad (masks < 16 stay inside the quad)
    #pragma unroll
    for (int r = 0; r < 4; ++r) {
        #pragma unroll
        for (int m = 8; m >= 1; m >>= 1) {
            p1[r] += __shfl_xor(p1[r], m);
            p2[r] += __shfl_xor(p2[r], m);
        }
    }
    if (n16 == 0) {
        #pragma unroll
        for (int r = 0; r < 4; ++r) {
            const int rr = wrow + quad * 4 + r;
            red1[rr][wave & 3] = p1[r];
            red2[rr][wave & 3] = p2[r];
        }
    }
    __syncthreads();
    if (tid < 32) {
        s1[row0 + tid] = red1[tid][0] + red1[tid][1] + red1[tid][2] + red1[tid][3];
        s2[row0 + tid] = red2[tid][0] + red2[tid][1] + red2[tid][2] + red2[tid][3];
    }
}

// out[b][i][j] = sigmoid(s1[b*1024+i] + s2[b*1024+j] + b1)
// grid = 8192 (one block per (b,i) row), 256 thr x float4 = 1024 j's
__global__ __launch_bounds__(256) void outer_sigmoid_kernel(
    const float* __restrict__ s1, const float* __restrict__ s2,
    const float* __restrict__ b1, float* __restrict__ out)
{
    const int bi = blockIdx.x;
    const int b  = bi >> 10;
    const float base = s1[bi] + b1[0];
    const float4 t = ((const float4*)(s2 + (b << 10)))[threadIdx.x];
    float4 r;
    r.x = 1.f / (1.f + __expf(-(base + t.x)));
    r.y = 1.f / (1.f + __expf(-(base + t.y)));
    r.z = 1.f / (1.f + __expf(-(base + t.z)));
    r.w = 1.f / (1.f + __expf(-(base + t.w)));
    ((float4*)out)[((size_t)bi << 8) + threadIdx.x] = r;
}

extern "C" void kernel_launch(void* const* d_in, const int* in_sizes, int n_in,
                              void* d_out, int out_size, void* d_ws, size_t ws_size,
                              hipStream_t stream)
{
    const float* text = (const float*)d_in[0];
    // d_in[1] = mask: all-ones, unused by the reference math
    const float* W0 = (const float*)d_in[2];
    const float* b0 = (const float*)d_in[3];
    const float* W1 = (const float*)d_in[4];
    const float* b1 = (const float*)d_in[5];
    float* out = (float*)d_out;

    // workspace layout: [s1: 32 KB][s2: 32 KB]
    float* s1 = (float*)d_ws;
    float* s2 = s1 + M_ROWS;

    gemm_s_kernel<<<256, 512, 0, stream>>>(text, W0, b0, W1, s1, s2);
    outer_sigmoid_kernel<<<8192, 256, 0, stream>>>(s1, s2, b1, out);
}